// Round 1
// baseline (483.506 us; speedup 1.0000x reference)
//
#include <hip/hip_runtime.h>
#include <hip/hip_bf16.h>
#include <stdint.h>

typedef short bf16x8 __attribute__((ext_vector_type(8)));
typedef float f32x4 __attribute__((ext_vector_type(4)));

#define BM 128
#define BN 128
#define BK 32

__device__ __forceinline__ unsigned short f2bf(float x) {
  uint32_t u = __builtin_bit_cast(uint32_t, x);
  u += 0x7FFFu + ((u >> 16) & 1u);
  return (unsigned short)(u >> 16);
}
__device__ __forceinline__ float bf2f(unsigned short u) {
  uint32_t v = ((uint32_t)u) << 16;
  return __builtin_bit_cast(float, v);
}

__device__ __forceinline__ void gl2lds16(const void* g, void* l) {
  __builtin_amdgcn_global_load_lds(
      (const __attribute__((address_space(1))) unsigned int*)g,
      (__attribute__((address_space(3))) unsigned int*)l, 16, 0, 0);
}

__global__ __launch_bounds__(256) void cast_f32_bf16_k(
    const float* __restrict__ s, unsigned short* __restrict__ d, long n) {
  long i = ((long)blockIdx.x * 256 + threadIdx.x) * 8;
  if (i >= n) return;
  float4 a = *(const float4*)(s + i);
  float4 b = *(const float4*)(s + i + 4);
  bf16x8 o;
  o[0] = (short)f2bf(a.x); o[1] = (short)f2bf(a.y);
  o[2] = (short)f2bf(a.z); o[3] = (short)f2bf(a.w);
  o[4] = (short)f2bf(b.x); o[5] = (short)f2bf(b.y);
  o[6] = (short)f2bf(b.z); o[7] = (short)f2bf(b.w);
  *(bf16x8*)(d + i) = o;
}

// C[M,N] = alpha * A[M,K] @ B[N,K]^T   (A,B bf16 row-major; C fp32 or bf16)
// blockIdx.z = batch, with element strides sA,sB,sC.
template <typename OutT>
__global__ __launch_bounds__(256) void gemm_bt(
    const unsigned short* __restrict__ A, const unsigned short* __restrict__ B,
    OutT* __restrict__ C, int M, int N, int K,
    long sA, long sB, long sC, float alpha) {
  __shared__ __align__(16) unsigned short lds[2][2][BM * BK];
  const int bz = blockIdx.z;
  A += (long)bz * sA; B += (long)bz * sB; C += (long)bz * sC;
  const int bm = blockIdx.y, bn = blockIdx.x;
  const int tid = threadIdx.x;
  const int lane = tid & 63;
  const int wave = tid >> 6;
  const int wm = wave >> 1, wn = wave & 1;

  const char* Abase = (const char*)(A + (long)bm * BM * K);
  const char* Bbase = (const char*)(B + (long)bn * BN * K);
  const long ldab = (long)K * 2;  // row stride in bytes

  f32x4 acc[4][4] = {};
  const int nsteps = K / BK;

  // stage one 128x32 A-tile and B-tile into lds[buf] (linear layout, 16B chunks)
  auto stage = [&](int buf, int kt) {
    const char* Ag = Abase + (long)kt * (BK * 2);
    const char* Bg = Bbase + (long)kt * (BK * 2);
#pragma unroll
    for (int c = 0; c < 2; ++c) {
      int lin = c * 256 + tid;        // 512 x 16B chunks per 8KB tile
      int row = lin >> 2;             // 4 chunks (64B) per row
      int colb = (lin & 3) << 4;      // byte offset within row
      gl2lds16(Ag + (long)row * ldab + colb, (char*)&lds[buf][0][0] + (long)lin * 16);
      gl2lds16(Bg + (long)row * ldab + colb, (char*)&lds[buf][1][0] + (long)lin * 16);
    }
  };

  stage(0, 0);
  __syncthreads();  // drains vmcnt before barrier
  int cur = 0;
  for (int kt = 0; kt < nsteps; ++kt) {
    if (kt + 1 < nsteps) stage(cur ^ 1, kt + 1);
    const unsigned short* la = &lds[cur][0][0];
    const unsigned short* lb = &lds[cur][1][0];
    bf16x8 af[4], bfg[4];
#pragma unroll
    for (int m = 0; m < 4; ++m)
      af[m] = *(const bf16x8*)(la + (wm * 64 + m * 16 + (lane & 15)) * BK + (lane >> 4) * 8);
#pragma unroll
    for (int n = 0; n < 4; ++n)
      bfg[n] = *(const bf16x8*)(lb + (wn * 64 + n * 16 + (lane & 15)) * BK + (lane >> 4) * 8);
#pragma unroll
    for (int m = 0; m < 4; ++m)
#pragma unroll
      for (int n = 0; n < 4; ++n)
        acc[m][n] = __builtin_amdgcn_mfma_f32_16x16x32_bf16(af[m], bfg[n], acc[m][n], 0, 0, 0);
    __syncthreads();  // waits vmcnt(0) (next tile staged) + lgkmcnt, syncs buffer reuse
    cur ^= 1;
  }

  // C/D layout: col = lane&15, row = (lane>>4)*4 + reg  [m89/m91 verified]
  const long row0 = (long)bm * BM + wm * 64 + (lane >> 4) * 4;
  const int col0 = bn * BN + wn * 64 + (lane & 15);
#pragma unroll
  for (int m = 0; m < 4; ++m) {
#pragma unroll
    for (int n = 0; n < 4; ++n) {
#pragma unroll
      for (int r = 0; r < 4; ++r) {
        long row = row0 + m * 16 + r;
        int col = col0 + n * 16;
        float v = acc[m][n][r] * alpha;
        if constexpr (sizeof(OutT) == 2)
          C[row * (long)N + col] = (OutT)f2bf(v);
        else
          C[row * (long)N + col] = v;
      }
    }
  }
}

// in-place row softmax on bf16 rows of length C (C == 2048, 256 thr * 8)
__global__ __launch_bounds__(256) void softmax_inplace(unsigned short* __restrict__ s, int C) {
  __shared__ float red[8];
  long row = blockIdx.x;
  unsigned short* p = s + row * (long)C;
  int tid = threadIdx.x, lane = tid & 63, w = tid >> 6;
  bf16x8 raw = *(const bf16x8*)(p + tid * 8);
  float v[8];
  float mx = -3.4e38f;
#pragma unroll
  for (int j = 0; j < 8; ++j) { v[j] = bf2f((unsigned short)raw[j]); mx = fmaxf(mx, v[j]); }
#pragma unroll
  for (int o = 32; o > 0; o >>= 1) mx = fmaxf(mx, __shfl_xor(mx, o));
  if (lane == 0) red[w] = mx;
  __syncthreads();
  mx = fmaxf(fmaxf(red[0], red[1]), fmaxf(red[2], red[3]));
  float sum = 0.f;
#pragma unroll
  for (int j = 0; j < 8; ++j) { v[j] = __expf(v[j] - mx); sum += v[j]; }
#pragma unroll
  for (int o = 32; o > 0; o >>= 1) sum += __shfl_xor(sum, o);
  if (lane == 0) red[4 + w] = sum;
  __syncthreads();
  float inv = 1.f / (red[4] + red[5] + red[6] + red[7]);
  bf16x8 o8;
#pragma unroll
  for (int j = 0; j < 8; ++j) o8[j] = (short)f2bf(v[j] * inv);
  *(bf16x8*)(p + tid * 8) = o8;
}

// out[b][c][r] = in[b][r][c]; R x C per batch
__global__ __launch_bounds__(256) void transpose_bf16(
    const unsigned short* __restrict__ in, unsigned short* __restrict__ out, int R, int C) {
  __shared__ unsigned short t[32][33];
  long b = blockIdx.z;
  in += b * (long)R * C; out += b * (long)R * C;
  int c0 = blockIdx.x * 32, r0 = blockIdx.y * 32;
  int tx = threadIdx.x & 31, ty = threadIdx.x >> 5;
#pragma unroll
  for (int i = 0; i < 4; ++i)
    t[ty + i * 8][tx] = in[(long)(r0 + ty + i * 8) * C + c0 + tx];
  __syncthreads();
#pragma unroll
  for (int i = 0; i < 4; ++i)
    out[(long)(c0 + ty + i * 8) * R + r0 + tx] = t[tx][ty + i * 8];
}

extern "C" void kernel_launch(void* const* d_in, const int* in_sizes, int n_in,
                              void* d_out, int out_size, void* d_ws, size_t ws_size,
                              hipStream_t stream) {
  (void)in_sizes; (void)n_in; (void)out_size; (void)ws_size;
  const float* x  = (const float*)d_in[0];
  const float* Wq = (const float*)d_in[1];
  const float* Wk = (const float*)d_in[2];
  const float* Wv = (const float*)d_in[3];
  const float* Wo = (const float*)d_in[4];
  const int B = 8, S = 2048, D = 1024;
  const long MB = 1 << 20;
  char* w = (char*)d_ws;
  // ws layout (peak 136 MB): weights 0..8MB, xb 8..40, qb 40..72, kb 72..104, vb 104..136
  unsigned short* Wqb = (unsigned short*)(w + 0 * MB);
  unsigned short* Wkb = (unsigned short*)(w + 2 * MB);
  unsigned short* Wvb = (unsigned short*)(w + 4 * MB);
  unsigned short* Wob = (unsigned short*)(w + 6 * MB);
  unsigned short* xb  = (unsigned short*)(w + 8 * MB);
  unsigned short* qb  = (unsigned short*)(w + 40 * MB);
  unsigned short* kb  = (unsigned short*)(w + 72 * MB);
  unsigned short* vb  = (unsigned short*)(w + 104 * MB);
  unsigned short* vt  = qb;  // q dead after QK^T
  unsigned short* wb  = xb;  // x dead after projections
  unsigned short* attn = (unsigned short*)d_out;  // bf16 scores: 8*2048*2048*2B == out bytes
  float* out = (float*)d_out;

  long nx = (long)B * S * D;
  long nw = (long)D * D;

  cast_f32_bf16_k<<<(int)(nx / 2048), 256, 0, stream>>>(x, xb, nx);
  cast_f32_bf16_k<<<(int)(nw / 2048), 256, 0, stream>>>(Wq, Wqb, nw);
  cast_f32_bf16_k<<<(int)(nw / 2048), 256, 0, stream>>>(Wk, Wkb, nw);
  cast_f32_bf16_k<<<(int)(nw / 2048), 256, 0, stream>>>(Wv, Wvb, nw);
  cast_f32_bf16_k<<<(int)(nw / 2048), 256, 0, stream>>>(Wo, Wob, nw);

  dim3 gP(D / BN, (B * S) / BM, 1);
  gemm_bt<unsigned short><<<gP, 256, 0, stream>>>(xb, Wqb, qb, B * S, D, D, 0, 0, 0, 1.f);
  gemm_bt<unsigned short><<<gP, 256, 0, stream>>>(xb, Wkb, kb, B * S, D, D, 0, 0, 0, 1.f);
  gemm_bt<unsigned short><<<gP, 256, 0, stream>>>(xb, Wvb, vb, B * S, D, D, 0, 0, 0, 1.f);

  // scores = (1/32) q @ k^T  -> bf16, stored in d_out
  dim3 gS(S / BN, S / BM, B);
  gemm_bt<unsigned short><<<gS, 256, 0, stream>>>(qb, kb, attn, S, S, D,
      (long)S * D, (long)S * D, (long)S * S, 0.03125f);

  // v^T into dead q-buffer
  dim3 gT(D / 32, S / 32, B);
  transpose_bf16<<<gT, 256, 0, stream>>>(vb, vt, S, D);

  softmax_inplace<<<B * S, 256, 0, stream>>>(attn, S);

  // weighted = attn @ v  (vt is [D][S] = B^T form) -> wb
  dim3 gPV(D / BN, S / BM, B);
  gemm_bt<unsigned short><<<gPV, 256, 0, stream>>>(attn, vt, wb, S, D, S,
      (long)S * S, (long)D * S, (long)S * D, 1.f);

  // out = weighted @ Wo^T  (fp32)
  gemm_bt<float><<<gP, 256, 0, stream>>>(wb, Wob, out, B * S, D, D, 0, 0, 0, 1.f);
}

// Round 2
// 365.316 us; speedup vs baseline: 1.3235x; 1.3235x over previous
//
#include <hip/hip_runtime.h>
#include <hip/hip_bf16.h>
#include <stdint.h>

typedef short bf16x8 __attribute__((ext_vector_type(8)));
typedef float f32x4 __attribute__((ext_vector_type(4)));

__device__ __forceinline__ unsigned short f2bf(float x) {
  uint32_t u = __builtin_bit_cast(uint32_t, x);
  u += 0x7FFFu + ((u >> 16) & 1u);
  return (unsigned short)(u >> 16);
}
__device__ __forceinline__ float bf2f(unsigned short u) {
  uint32_t v = ((uint32_t)u) << 16;
  return __builtin_bit_cast(float, v);
}

__device__ __forceinline__ void gl2lds16(const void* g, void* l) {
  __builtin_amdgcn_global_load_lds(
      (const __attribute__((address_space(1))) unsigned int*)g,
      (__attribute__((address_space(3))) unsigned int*)l, 16, 0, 0);
}

__global__ __launch_bounds__(256) void cast_f32_bf16_k(
    const float* __restrict__ s, unsigned short* __restrict__ d, long n) {
  long i = ((long)blockIdx.x * 256 + threadIdx.x) * 8;
  if (i >= n) return;
  float4 a = *(const float4*)(s + i);
  float4 b = *(const float4*)(s + i + 4);
  bf16x8 o;
  o[0] = (short)f2bf(a.x); o[1] = (short)f2bf(a.y);
  o[2] = (short)f2bf(a.z); o[3] = (short)f2bf(a.w);
  o[4] = (short)f2bf(b.x); o[5] = (short)f2bf(b.y);
  o[6] = (short)f2bf(b.z); o[7] = (short)f2bf(b.w);
  *(bf16x8*)(d + i) = o;
}

// cast 4 equally-sized fp32 arrays to one contiguous bf16 dest (z selects src)
__global__ __launch_bounds__(256) void cast4_f32_bf16_k(
    const float* __restrict__ s0, const float* __restrict__ s1,
    const float* __restrict__ s2, const float* __restrict__ s3,
    unsigned short* __restrict__ d, long n) {
  const float* s = blockIdx.z == 0 ? s0 : blockIdx.z == 1 ? s1 : blockIdx.z == 2 ? s2 : s3;
  long i = ((long)blockIdx.x * 256 + threadIdx.x) * 8;
  if (i >= n) return;
  float4 a = *(const float4*)(s + i);
  float4 b = *(const float4*)(s + i + 4);
  bf16x8 o;
  o[0] = (short)f2bf(a.x); o[1] = (short)f2bf(a.y);
  o[2] = (short)f2bf(a.z); o[3] = (short)f2bf(a.w);
  o[4] = (short)f2bf(b.x); o[5] = (short)f2bf(b.y);
  o[6] = (short)f2bf(b.z); o[7] = (short)f2bf(b.w);
  *(bf16x8*)(d + blockIdx.z * n + i) = o;
}

// ============================================================================
// 256x256 8-phase GEMM: C[M,N] = alpha * A[M,K] @ B[N,K]^T  (bf16 in, OutT out)
// 512 thr = 8 waves (2 x 4). BK=64 split in two k-half regions [256][32].
// LDS: [dbuf][op][khalf] x 16KB = 128KB. XOR swizzle byte^=((row&3)<<4) via
// pre-swizzled global source (linear global_load_lds dest) + swizzled ds_read.
// Counted vmcnt(4) at each phase end; raw s_barrier (no drain); setprio(1)
// around each 16-MFMA cluster. Uniform schedule: during tile t's 4 phases,
// stage tile t+1's regions in order A-k0, B-k0, A-k1, B-k1 into buf (t+1)&1.
// ============================================================================
template <typename OutT>
__global__ __launch_bounds__(512, 2) void gemm_bt8(
    const unsigned short* __restrict__ A, const unsigned short* __restrict__ B,
    OutT* __restrict__ C, int M, int N, int K,
    long sA, long sB, long sC, float alpha) {
  extern __shared__ __align__(16) char smem[];
  const int bz = blockIdx.z;
  // bijective XCD swizzle (requires gridDim.x*gridDim.y % 8 == 0)
  const int gx = gridDim.x;
  const int nwg = gx * gridDim.y;
  const int idx = blockIdx.y * gx + blockIdx.x;
  const int wg = (idx & 7) * (nwg >> 3) + (idx >> 3);
  const int bm = wg / gx, bn = wg % gx;

  const int tid = threadIdx.x, lane = tid & 63, wave = tid >> 6;
  const int wm = wave >> 2, wn = wave & 3;

  const char* Ac = (const char*)(A + (long)bz * sA + (long)bm * 256 * K);
  const char* Bc = (const char*)(B + (long)bz * sB + (long)bn * 256 * K);
  C += (long)bz * sC;
  const long ld = (long)K * 2;  // row stride bytes (A and B both [*][K])

  // staging source precompute: dest chunk d -> logical p -> (row, col)
  int srow[2], scol[2];
#pragma unroll
  for (int c = 0; c < 2; ++c) {
    int d = ((wave << 1 | c) << 10) + (lane << 4);
    int p = d ^ (((d >> 6) & 3) << 4);
    srow[c] = p >> 6; scol[c] = p & 63;
  }

  auto stageReg = [&](int dstbuf, int op, int kh, const char* gbase, int ktb) {
    char* reg = smem + (((dstbuf << 1 | op) << 1 | kh) << 14);
#pragma unroll
    for (int c = 0; c < 2; ++c) {
      gl2lds16(gbase + (long)srow[c] * ld + (ktb + kh * 64 + scol[c]),
               reg + ((wave << 1 | c) << 10) + (lane << 4));
    }
  };

  // ds_read addressing (swizzled): logical p = row*64 + (lane>>4)*16,
  // d = p ^ ((row&3)<<4);  row&3 == lane&3 for all our rows (row = base + lane&15,
  // base multiple of 16)
  const int colx = (((lane >> 4) ^ (lane & 3)) << 4);
  const int rbA = (wm * 128 + (lane & 15)) * 64;
  const int rbB = (wn * 64 + (lane & 15)) * 64;

  // prologue: stage tile 0 into buf 0 (order A-k0, B-k0, A-k1, B-k1)
#pragma unroll
  for (int ph = 0; ph < 4; ++ph)
    stageReg(0, ph & 1, ph >> 1, (ph & 1) ? Bc : Ac, 0);
  asm volatile("s_waitcnt vmcnt(4)" ::: "memory");
  __builtin_amdgcn_s_barrier();
  __builtin_amdgcn_sched_barrier(0);

  f32x4 acc[8][4] = {};
  bf16x8 bfr[4];
  const int nt = K >> 6;
  for (int t = 0; t < nt; ++t) {
    const int b = t & 1;
    const int ktb = (t + 1 < nt ? t + 1 : 0) << 7;  // last iter: junk-restage tile 0
#pragma unroll
    for (int ph = 0; ph < 4; ++ph) {
      const int g = ph & 1, kh = ph >> 1;
      // stage one region of tile t+1 into buf b^1
      stageReg(b ^ 1, ph & 1, ph >> 1, (ph & 1) ? Bc : Ac, ktb);
      // ds-read fragments for this phase from buf b
      const char* regA = smem + (((b << 1 | 0) << 1 | kh) << 14);
      const char* regB = smem + (((b << 1 | 1) << 1 | kh) << 14);
      bf16x8 afr[4];
#pragma unroll
      for (int m = 0; m < 4; ++m)
        afr[m] = *(const bf16x8*)(regA + rbA + g * 4096 + m * 1024 + colx);
      if (g == 0) {
#pragma unroll
        for (int n = 0; n < 4; ++n)
          bfr[n] = *(const bf16x8*)(regB + rbB + n * 1024 + colx);
      }
      __builtin_amdgcn_s_barrier();
      asm volatile("s_waitcnt lgkmcnt(0)" ::: "memory");
      __builtin_amdgcn_sched_barrier(0);
      __builtin_amdgcn_s_setprio(1);
#pragma unroll
      for (int m = 0; m < 4; ++m)
#pragma unroll
        for (int n = 0; n < 4; ++n)
          acc[g * 4 + m][n] = __builtin_amdgcn_mfma_f32_16x16x32_bf16(
              afr[m], bfr[n], acc[g * 4 + m][n], 0, 0, 0);
      __builtin_amdgcn_s_setprio(0);
      asm volatile("s_waitcnt vmcnt(4)" ::: "memory");
      __builtin_amdgcn_s_barrier();
      __builtin_amdgcn_sched_barrier(0);
    }
  }

  // epilogue: C/D layout col=lane&15, row=(lane>>4)*4+reg  [m89/m91 verified]
  const long row0 = (long)bm * 256 + wm * 128 + (lane >> 4) * 4;
  const int col0 = bn * 256 + wn * 64 + (lane & 15);
#pragma unroll
  for (int m = 0; m < 8; ++m) {
#pragma unroll
    for (int n = 0; n < 4; ++n) {
#pragma unroll
      for (int r = 0; r < 4; ++r) {
        long row = row0 + m * 16 + r;
        int col = col0 + n * 16;
        float v = acc[m][n][r] * alpha;
        if constexpr (sizeof(OutT) == 2)
          C[row * (long)N + col] = (OutT)f2bf(v);
        else
          C[row * (long)N + col] = v;
      }
    }
  }
}

// in-place row softmax on bf16 rows of length C (C == 2048, 256 thr * 8)
__global__ __launch_bounds__(256) void softmax_inplace(unsigned short* __restrict__ s, int C) {
  __shared__ float red[8];
  long row = blockIdx.x;
  unsigned short* p = s + row * (long)C;
  int tid = threadIdx.x, lane = tid & 63, w = tid >> 6;
  bf16x8 raw = *(const bf16x8*)(p + tid * 8);
  float v[8];
  float mx = -3.4e38f;
#pragma unroll
  for (int j = 0; j < 8; ++j) { v[j] = bf2f((unsigned short)raw[j]); mx = fmaxf(mx, v[j]); }
#pragma unroll
  for (int o = 32; o > 0; o >>= 1) mx = fmaxf(mx, __shfl_xor(mx, o));
  if (lane == 0) red[w] = mx;
  __syncthreads();
  mx = fmaxf(fmaxf(red[0], red[1]), fmaxf(red[2], red[3]));
  float sum = 0.f;
#pragma unroll
  for (int j = 0; j < 8; ++j) { v[j] = __expf(v[j] - mx); sum += v[j]; }
#pragma unroll
  for (int o = 32; o > 0; o >>= 1) sum += __shfl_xor(sum, o);
  if (lane == 0) red[4 + w] = sum;
  __syncthreads();
  float inv = 1.f / (red[4] + red[5] + red[6] + red[7]);
  bf16x8 o8;
#pragma unroll
  for (int j = 0; j < 8; ++j) o8[j] = (short)f2bf(v[j] * inv);
  *(bf16x8*)(p + tid * 8) = o8;
}

// out[b][c][r] = in[b][r][c]; R x C per batch
__global__ __launch_bounds__(256) void transpose_bf16(
    const unsigned short* __restrict__ in, unsigned short* __restrict__ out, int R, int C) {
  __shared__ unsigned short t[32][33];
  long b = blockIdx.z;
  in += b * (long)R * C; out += b * (long)R * C;
  int c0 = blockIdx.x * 32, r0 = blockIdx.y * 32;
  int tx = threadIdx.x & 31, ty = threadIdx.x >> 5;
#pragma unroll
  for (int i = 0; i < 4; ++i)
    t[ty + i * 8][tx] = in[(long)(r0 + ty + i * 8) * C + c0 + tx];
  __syncthreads();
#pragma unroll
  for (int i = 0; i < 4; ++i)
    out[(long)(c0 + ty + i * 8) * R + r0 + tx] = t[tx][ty + i * 8];
}

extern "C" void kernel_launch(void* const* d_in, const int* in_sizes, int n_in,
                              void* d_out, int out_size, void* d_ws, size_t ws_size,
                              hipStream_t stream) {
  (void)in_sizes; (void)n_in; (void)out_size; (void)ws_size;
  const float* x  = (const float*)d_in[0];
  const float* Wq = (const float*)d_in[1];
  const float* Wk = (const float*)d_in[2];
  const float* Wv = (const float*)d_in[3];
  const float* Wo = (const float*)d_in[4];
  const int B = 8, S = 2048, D = 1024;
  const long MB = 1 << 20;
  char* w = (char*)d_ws;
  unsigned short* Wqb = (unsigned short*)(w + 0 * MB);
  unsigned short* Wkb = (unsigned short*)(w + 2 * MB);
  unsigned short* Wvb = (unsigned short*)(w + 4 * MB);
  unsigned short* Wob = (unsigned short*)(w + 6 * MB);
  unsigned short* xb  = (unsigned short*)(w + 8 * MB);
  unsigned short* qb  = (unsigned short*)(w + 40 * MB);
  unsigned short* kb  = (unsigned short*)(w + 72 * MB);
  unsigned short* vb  = (unsigned short*)(w + 104 * MB);
  unsigned short* vt  = qb;  // q dead after QK^T
  unsigned short* wb  = xb;  // x dead after projections
  unsigned short* attn = (unsigned short*)d_out;  // bf16 scores fill d_out exactly
  float* out = (float*)d_out;

  long nx = (long)B * S * D;
  long nw = (long)D * D;

  const int LDSB = 131072;
  hipFuncSetAttribute((const void*)gemm_bt8<unsigned short>,
                      hipFuncAttributeMaxDynamicSharedMemorySize, LDSB);
  hipFuncSetAttribute((const void*)gemm_bt8<float>,
                      hipFuncAttributeMaxDynamicSharedMemorySize, LDSB);

  cast_f32_bf16_k<<<(int)(nx / 2048), 256, 0, stream>>>(x, xb, nx);
  dim3 gW((int)(nw / 2048), 1, 4);
  cast4_f32_bf16_k<<<gW, 256, 0, stream>>>(Wq, Wk, Wv, Wo, Wqb, nw);

  // projections: M=16384, N=1024, K=1024
  dim3 gP(D / 256, (B * S) / 256, 1);
  gemm_bt8<unsigned short><<<gP, 512, LDSB, stream>>>(xb, Wqb, qb, B * S, D, D, 0, 0, 0, 1.f);
  gemm_bt8<unsigned short><<<gP, 512, LDSB, stream>>>(xb, Wkb, kb, B * S, D, D, 0, 0, 0, 1.f);
  gemm_bt8<unsigned short><<<gP, 512, LDSB, stream>>>(xb, Wvb, vb, B * S, D, D, 0, 0, 0, 1.f);

  // scores = (1/32) q @ k^T -> bf16 in d_out
  dim3 gS(S / 256, S / 256, B);
  gemm_bt8<unsigned short><<<gS, 512, LDSB, stream>>>(qb, kb, attn, S, S, D,
      (long)S * D, (long)S * D, (long)S * S, 0.03125f);

  // v^T into dead q-buffer
  dim3 gT(D / 32, S / 32, B);
  transpose_bf16<<<gT, 256, 0, stream>>>(vb, vt, S, D);

  softmax_inplace<<<B * S, 256, 0, stream>>>(attn, S);

  // weighted = attn @ v  (vt is [D][S]) : M=2048/batch, N=1024, K=2048
  dim3 gPV(D / 256, S / 256, B);
  gemm_bt8<unsigned short><<<gPV, 512, LDSB, stream>>>(attn, vt, wb, S, D, S,
      (long)S * S, (long)D * S, (long)S * D, 1.f);

  // out = weighted @ Wo^T (fp32): M=16384, N=1024, K=1024
  gemm_bt8<float><<<gP, 512, LDSB, stream>>>(wb, Wob, out, B * S, D, D, 0, 0, 0, 1.f);
}

// Round 3
// 346.457 us; speedup vs baseline: 1.3956x; 1.0544x over previous
//
#include <hip/hip_runtime.h>
#include <hip/hip_bf16.h>
#include <stdint.h>

typedef short bf16x8 __attribute__((ext_vector_type(8)));
typedef float f32x4 __attribute__((ext_vector_type(4)));

__device__ __forceinline__ unsigned short f2bf(float x) {
  uint32_t u = __builtin_bit_cast(uint32_t, x);
  u += 0x7FFFu + ((u >> 16) & 1u);
  return (unsigned short)(u >> 16);
}
__device__ __forceinline__ float bf2f(unsigned short u) {
  uint32_t v = ((uint32_t)u) << 16;
  return __builtin_bit_cast(float, v);
}

__device__ __forceinline__ void gl2lds16(const void* g, void* l) {
  __builtin_amdgcn_global_load_lds(
      (const __attribute__((address_space(1))) unsigned int*)g,
      (__attribute__((address_space(3))) unsigned int*)l, 16, 0, 0);
}

__global__ __launch_bounds__(256) void cast_f32_bf16_k(
    const float* __restrict__ s, unsigned short* __restrict__ d, long n) {
  long i = ((long)blockIdx.x * 256 + threadIdx.x) * 8;
  if (i >= n) return;
  float4 a = *(const float4*)(s + i);
  float4 b = *(const float4*)(s + i + 4);
  bf16x8 o;
  o[0] = (short)f2bf(a.x); o[1] = (short)f2bf(a.y);
  o[2] = (short)f2bf(a.z); o[3] = (short)f2bf(a.w);
  o[4] = (short)f2bf(b.x); o[5] = (short)f2bf(b.y);
  o[6] = (short)f2bf(b.z); o[7] = (short)f2bf(b.w);
  *(bf16x8*)(d + i) = o;
}

__global__ __launch_bounds__(256) void cast4_f32_bf16_k(
    const float* __restrict__ s0, const float* __restrict__ s1,
    const float* __restrict__ s2, const float* __restrict__ s3,
    unsigned short* __restrict__ d, long n) {
  const float* s = blockIdx.z == 0 ? s0 : blockIdx.z == 1 ? s1 : blockIdx.z == 2 ? s2 : s3;
  long i = ((long)blockIdx.x * 256 + threadIdx.x) * 8;
  if (i >= n) return;
  float4 a = *(const float4*)(s + i);
  float4 b = *(const float4*)(s + i + 4);
  bf16x8 o;
  o[0] = (short)f2bf(a.x); o[1] = (short)f2bf(a.y);
  o[2] = (short)f2bf(a.z); o[3] = (short)f2bf(a.w);
  o[4] = (short)f2bf(b.x); o[5] = (short)f2bf(b.y);
  o[6] = (short)f2bf(b.z); o[7] = (short)f2bf(b.w);
  *(bf16x8*)(d + blockIdx.z * n + i) = o;
}

// ============================================================================
// 256x256 8-phase GEMM: C[M,N] = alpha * A[M,K] @ B[N,K]^T  (bf16 in)
// 512 thr = 8 waves (2 x 4). BK=64. LDS regions [buf][op] = [256 rows][128B],
// 32KB each, 128KB total. Swizzle: phys_col = col ^ ((row&7)<<4)  -> every
// ds_read_b128 wave-access is bank-uniform (8 acc/bank = b128 floor).
// Staged linearly by global_load_lds from pre-swizzled global source.
// 4 phases/K-tile (g-half x k-half), 16 MFMA each; stage 2 chunks/phase into
// buf^1; single vmcnt(0) at tile boundary (loads issued >=1 tile early).
// TRANSV: epilogue writes V^T per-batch [D][S] (ushort4 along s).
// ============================================================================
template <typename OutT, bool TRANSV>
__global__ __launch_bounds__(512, 2) void gemm_bt8(
    const unsigned short* __restrict__ A, const unsigned short* __restrict__ B,
    OutT* __restrict__ C, int M, int N, int K,
    long sA, long sB, long sC, float alpha) {
  extern __shared__ __align__(16) char smem[];
  const int bz = blockIdx.z;
  const int gx = gridDim.x;
  const int nwg = gx * gridDim.y;  // must be %8==0
  const int idx = blockIdx.y * gx + blockIdx.x;
  const int wg = (idx & 7) * (nwg >> 3) + (idx >> 3);
  const int bm = wg / gx, bn = wg % gx;

  const int tid = threadIdx.x, lane = tid & 63, wave = tid >> 6;
  const int wm = wave >> 2, wn = wave & 3;

  const char* Ac = (const char*)(A + (long)bz * sA + (long)bm * 256 * K);
  const char* Bc = (const char*)(B + (long)bz * sB + (long)bn * 256 * K);
  C += (long)bz * sC;
  const long ld = (long)K * 2;

  // staging: dest byte d = c*8192 + tid*16 in region; row = d>>7, pcol = d&127,
  // logical col = pcol ^ ((row&7)<<4)
  const int sr = tid >> 3;                                    // row within chunk (0..63)
  const int scol = (((tid & 7) ^ ((tid >> 3) & 7)) << 4);     // pre-swizzled source col

  auto stageChunk = [&](int buf, int op, int c, const char* gbase, int ktb) {
    char* reg = smem + ((buf * 2 + op) << 15);
    gl2lds16(gbase + (long)(sr + c * 64) * ld + (ktb + scol),
             reg + c * 8192 + tid * 16);
  };

  // read addressing: row = rbase + (lane&15); row&7 == lane&7.
  // phys col = (kh<<6 | (lane>>4)<<4) ^ ((lane&7)<<4)
  const int colx0 = ((lane >> 4) << 4) ^ ((lane & 7) << 4);   // kh=0
  const int colx1 = (64 | ((lane >> 4) << 4)) ^ ((lane & 7) << 4);  // kh=1
  const int rbA = (wm * 128 + (lane & 15)) * 128;
  const int rbB = (wn * 64 + (lane & 15)) * 128;

  // prologue: stage all 8 chunks of tile 0 into buf 0
#pragma unroll
  for (int c = 0; c < 4; ++c) stageChunk(0, 0, c, Ac, 0);
#pragma unroll
  for (int c = 0; c < 4; ++c) stageChunk(0, 1, c, Bc, 0);
  asm volatile("s_waitcnt vmcnt(0)" ::: "memory");
  __builtin_amdgcn_s_barrier();
  __builtin_amdgcn_sched_barrier(0);

  f32x4 acc[8][4] = {};
  bf16x8 bfr[4];
  const int nt = K >> 6;
  for (int t = 0; t < nt; ++t) {
    const int b = t & 1;
    const int ktb = (t + 1 < nt ? t + 1 : 0) << 7;  // last iter: junk-restage tile 0
#pragma unroll
    for (int ph = 0; ph < 4; ++ph) {
      const int g = ph & 1, kh = ph >> 1;
      const int colx = kh ? colx1 : colx0;
      // stage 2 chunks of tile t+1 into buf b^1 (A chunks first, then B)
      stageChunk(b ^ 1, ph >> 1, (ph & 1) * 2 + 0, (ph >> 1) ? Bc : Ac, ktb);
      stageChunk(b ^ 1, ph >> 1, (ph & 1) * 2 + 1, (ph >> 1) ? Bc : Ac, ktb);
      // ds-read fragments from buf b
      const char* regA = smem + ((b * 2 + 0) << 15);
      const char* regB = smem + ((b * 2 + 1) << 15);
      bf16x8 afr[4];
#pragma unroll
      for (int m = 0; m < 4; ++m)
        afr[m] = *(const bf16x8*)(regA + rbA + g * (64 * 128) + m * (16 * 128) + colx);
      if (g == 0) {
#pragma unroll
        for (int n = 0; n < 4; ++n)
          bfr[n] = *(const bf16x8*)(regB + rbB + n * (16 * 128) + colx);
      }
      __builtin_amdgcn_s_barrier();
      asm volatile("s_waitcnt lgkmcnt(0)" ::: "memory");
      __builtin_amdgcn_sched_barrier(0);
      __builtin_amdgcn_s_setprio(1);
#pragma unroll
      for (int m = 0; m < 4; ++m)
#pragma unroll
        for (int n = 0; n < 4; ++n)
          acc[g * 4 + m][n] = __builtin_amdgcn_mfma_f32_16x16x32_bf16(
              afr[m], bfr[n], acc[g * 4 + m][n], 0, 0, 0);
      __builtin_amdgcn_s_setprio(0);
      if (ph == 3) asm volatile("s_waitcnt vmcnt(0)" ::: "memory");
      __builtin_amdgcn_s_barrier();
      __builtin_amdgcn_sched_barrier(0);
    }
  }

  // epilogue: C/D layout col=lane&15, row=(lane>>4)*4+reg  [m89/m91 verified]
  const long row0 = (long)bm * 256 + wm * 128 + (lane >> 4) * 4;
  const int col0 = bn * 256 + wn * 64 + (lane & 15);
#pragma unroll
  for (int m = 0; m < 8; ++m) {
#pragma unroll
    for (int n = 0; n < 4; ++n) {
      if constexpr (TRANSV) {
        // v^T per batch: b = row>>11, s = row&2047; vt[b*2^21 + col*2048 + s]
        long row = row0 + m * 16;
        long base = ((row >> 11) << 21) + ((long)(col0 + n * 16) << 11) + (row & 2047);
        ushort4 st;
        st.x = f2bf(acc[m][n][0]); st.y = f2bf(acc[m][n][1]);
        st.z = f2bf(acc[m][n][2]); st.w = f2bf(acc[m][n][3]);
        *(ushort4*)((unsigned short*)C + base) = st;
      } else {
#pragma unroll
        for (int r = 0; r < 4; ++r) {
          long row = row0 + m * 16 + r;
          int col = col0 + n * 16;
          float v = acc[m][n][r] * alpha;
          if constexpr (sizeof(OutT) == 2)
            C[row * (long)N + col] = (OutT)f2bf(v);
          else
            C[row * (long)N + col] = v;
        }
      }
    }
  }
}

// in-place row softmax on bf16 rows of length C (C == 2048, 256 thr * 8)
__global__ __launch_bounds__(256) void softmax_inplace(unsigned short* __restrict__ s, int C) {
  __shared__ float red[8];
  long row = blockIdx.x;
  unsigned short* p = s + row * (long)C;
  int tid = threadIdx.x, lane = tid & 63, w = tid >> 6;
  bf16x8 raw = *(const bf16x8*)(p + tid * 8);
  float v[8];
  float mx = -3.4e38f;
#pragma unroll
  for (int j = 0; j < 8; ++j) { v[j] = bf2f((unsigned short)raw[j]); mx = fmaxf(mx, v[j]); }
#pragma unroll
  for (int o = 32; o > 0; o >>= 1) mx = fmaxf(mx, __shfl_xor(mx, o));
  if (lane == 0) red[w] = mx;
  __syncthreads();
  mx = fmaxf(fmaxf(red[0], red[1]), fmaxf(red[2], red[3]));
  float sum = 0.f;
#pragma unroll
  for (int j = 0; j < 8; ++j) { v[j] = __expf(v[j] - mx); sum += v[j]; }
#pragma unroll
  for (int o = 32; o > 0; o >>= 1) sum += __shfl_xor(sum, o);
  if (lane == 0) red[4 + w] = sum;
  __syncthreads();
  float inv = 1.f / (red[4] + red[5] + red[6] + red[7]);
  bf16x8 o8;
#pragma unroll
  for (int j = 0; j < 8; ++j) o8[j] = (short)f2bf(v[j] * inv);
  *(bf16x8*)(p + tid * 8) = o8;
}

extern "C" void kernel_launch(void* const* d_in, const int* in_sizes, int n_in,
                              void* d_out, int out_size, void* d_ws, size_t ws_size,
                              hipStream_t stream) {
  (void)in_sizes; (void)n_in; (void)out_size; (void)ws_size;
  const float* x  = (const float*)d_in[0];
  const float* Wq = (const float*)d_in[1];
  const float* Wk = (const float*)d_in[2];
  const float* Wv = (const float*)d_in[3];
  const float* Wo = (const float*)d_in[4];
  const int B = 8, S = 2048, D = 1024;
  const long MB = 1 << 20;
  char* w = (char*)d_ws;
  unsigned short* Wqb = (unsigned short*)(w + 0 * MB);
  unsigned short* Wkb = (unsigned short*)(w + 2 * MB);
  unsigned short* Wvb = (unsigned short*)(w + 4 * MB);
  unsigned short* Wob = (unsigned short*)(w + 6 * MB);
  unsigned short* xb  = (unsigned short*)(w + 8 * MB);
  unsigned short* qb  = (unsigned short*)(w + 40 * MB);
  unsigned short* kb  = (unsigned short*)(w + 72 * MB);
  unsigned short* vt  = (unsigned short*)(w + 104 * MB);  // V^T written directly
  unsigned short* wb  = xb;  // x dead after projections
  unsigned short* attn = (unsigned short*)d_out;
  float* out = (float*)d_out;

  long nx = (long)B * S * D;
  long nw = (long)D * D;

  const int LDSB = 131072;
  hipFuncSetAttribute((const void*)gemm_bt8<unsigned short, false>,
                      hipFuncAttributeMaxDynamicSharedMemorySize, LDSB);
  hipFuncSetAttribute((const void*)gemm_bt8<unsigned short, true>,
                      hipFuncAttributeMaxDynamicSharedMemorySize, LDSB);
  hipFuncSetAttribute((const void*)gemm_bt8<float, false>,
                      hipFuncAttributeMaxDynamicSharedMemorySize, LDSB);

  cast_f32_bf16_k<<<(int)(nx / 2048), 256, 0, stream>>>(x, xb, nx);
  dim3 gW((int)(nw / 2048), 1, 4);
  cast4_f32_bf16_k<<<gW, 256, 0, stream>>>(Wq, Wk, Wv, Wo, Wqb, nw);

  // projections: M=16384, N=1024, K=1024
  dim3 gP(D / 256, (B * S) / 256, 1);
  gemm_bt8<unsigned short, false><<<gP, 512, LDSB, stream>>>(xb, Wqb, qb, B * S, D, D, 0, 0, 0, 1.f);
  gemm_bt8<unsigned short, false><<<gP, 512, LDSB, stream>>>(xb, Wkb, kb, B * S, D, D, 0, 0, 0, 1.f);
  // V projection writes v^T [B][D][S] directly
  gemm_bt8<unsigned short, true><<<gP, 512, LDSB, stream>>>(xb, Wvb, vt, B * S, D, D, 0, 0, 0, 1.f);

  // scores = (1/32) q @ k^T -> bf16 in d_out
  dim3 gS(S / 256, S / 256, B);
  gemm_bt8<unsigned short, false><<<gS, 512, LDSB, stream>>>(qb, kb, attn, S, S, D,
      (long)S * D, (long)S * D, (long)S * S, 0.03125f);

  softmax_inplace<<<B * S, 256, 0, stream>>>(attn, S);

  // weighted = attn @ v  (vt is [D][S]) : per batch M=2048, N=1024, K=2048
  dim3 gPV(D / 256, S / 256, B);
  gemm_bt8<unsigned short, false><<<gPV, 512, LDSB, stream>>>(attn, vt, wb, S, D, S,
      (long)S * S, (long)D * S, (long)S * D, 1.f);

  // out = weighted @ Wo^T (fp32): M=16384, N=1024, K=1024
  gemm_bt8<float, false><<<gP, 512, LDSB, stream>>>(wb, Wob, out, B * S, D, D, 0, 0, 0, 1.f);
}

// Round 5
// 324.409 us; speedup vs baseline: 1.4904x; 1.0680x over previous
//
#include <hip/hip_runtime.h>
#include <hip/hip_bf16.h>
#include <stdint.h>

typedef short bf16x8 __attribute__((ext_vector_type(8)));
typedef float f32x4 __attribute__((ext_vector_type(4)));

__device__ __forceinline__ unsigned short f2bf(float x) {
  uint32_t u = __builtin_bit_cast(uint32_t, x);
  u += 0x7FFFu + ((u >> 16) & 1u);
  return (unsigned short)(u >> 16);
}
__device__ __forceinline__ float bf2f(unsigned short u) {
  uint32_t v = ((uint32_t)u) << 16;
  return __builtin_bit_cast(float, v);
}

__device__ __forceinline__ void gl2lds16(const void* g, void* l) {
  __builtin_amdgcn_global_load_lds(
      (const __attribute__((address_space(1))) unsigned int*)g,
      (__attribute__((address_space(3))) unsigned int*)l, 16, 0, 0);
}

__global__ __launch_bounds__(256) void cast_f32_bf16_k(
    const float* __restrict__ s, unsigned short* __restrict__ d, long n) {
  long i = ((long)blockIdx.x * 256 + threadIdx.x) * 8;
  if (i >= n) return;
  float4 a = *(const float4*)(s + i);
  float4 b = *(const float4*)(s + i + 4);
  bf16x8 o;
  o[0] = (short)f2bf(a.x); o[1] = (short)f2bf(a.y);
  o[2] = (short)f2bf(a.z); o[3] = (short)f2bf(a.w);
  o[4] = (short)f2bf(b.x); o[5] = (short)f2bf(b.y);
  o[6] = (short)f2bf(b.z); o[7] = (short)f2bf(b.w);
  *(bf16x8*)(d + i) = o;
}

__global__ __launch_bounds__(256) void cast4_f32_bf16_k(
    const float* __restrict__ s0, const float* __restrict__ s1,
    const float* __restrict__ s2, const float* __restrict__ s3,
    unsigned short* __restrict__ d, long n) {
  const float* s = blockIdx.z == 0 ? s0 : blockIdx.z == 1 ? s1 : blockIdx.z == 2 ? s2 : s3;
  long i = ((long)blockIdx.x * 256 + threadIdx.x) * 8;
  if (i >= n) return;
  float4 a = *(const float4*)(s + i);
  float4 b = *(const float4*)(s + i + 4);
  bf16x8 o;
  o[0] = (short)f2bf(a.x); o[1] = (short)f2bf(a.y);
  o[2] = (short)f2bf(a.z); o[3] = (short)f2bf(a.w);
  o[4] = (short)f2bf(b.x); o[5] = (short)f2bf(b.y);
  o[6] = (short)f2bf(b.z); o[7] = (short)f2bf(b.w);
  *(bf16x8*)(d + blockIdx.z * n + i) = o;
}

// ============================================================================
// 256x256 pipelined GEMM: C = alpha * A[M,K] @ B[N,K]^T  (bf16 in)
// 8 waves (2Mx4N), BK=64, LDS 4x32KB regions [256 rows][128B], XOR swizzle
// phys_col = col ^ ((row&7)<<4) (conflict-free, verified R3: 0 conflicts).
// Pipelining: phase p issues ds_reads for phase p+1's fragments, then waits
// COUNTED lgkmcnt(N_just_issued) so only phase-p frags (issued at p-1) must
// have landed -> LDS pipe drains under MFMA. All 8 stage chunks for tile t+1
// issue in phases 0-1; phase 3's vmcnt(0) covers loads >=2 phases old (~0
// stall), then cross-tile frag reads issue and land under phase-3 MFMA.
// NOTE: mfma16's g argument is the M-HALF index (0/1), NOT the phase index —
// kh=1 phases accumulate into the SAME acc groups (R4 bug: passed 2,3 -> OOB).
// FUSEQKV: B = [Wq;Wk;Wv] (N=3072); per-bn tensor routing, V written
// transposed per batch as [D][S].
// ============================================================================
template <typename OutT, bool FUSEQKV>
__global__ __launch_bounds__(512, 2) void gemm_bt8(
    const unsigned short* __restrict__ A, const unsigned short* __restrict__ B,
    OutT* __restrict__ C, int M, int N, int K,
    long sA, long sB, long sC, float alpha) {
  extern __shared__ __align__(16) char smem[];
  const int bz = blockIdx.z;
  const int gx = gridDim.x;
  const int nwg = gx * gridDim.y;  // must be %8==0
  const int idx = blockIdx.y * gx + blockIdx.x;
  const int wg = (idx & 7) * (nwg >> 3) + (idx >> 3);
  const int bm = wg / gx, bn = wg % gx;

  const int tid = threadIdx.x, lane = tid & 63, wave = tid >> 6;
  const int wm = wave >> 2, wn = wave & 3;

  const char* Ac = (const char*)(A + (long)bz * sA + (long)bm * 256 * K);
  const char* Bc = (const char*)(B + (long)bz * sB + (long)bn * 256 * K);
  C += (long)bz * sC;
  const long ld = (long)K * 2;

  // staging: chunk c covers rows [c*64, c*64+64); dest d = c*8192 + tid*16
  const int sr = tid >> 3;
  const int scol = (((tid & 7) ^ ((tid >> 3) & 7)) << 4);  // pre-swizzled col

  auto stageChunk = [&](int buf, int op, int c, const char* gbase, int ktb) {
    char* reg = smem + ((buf * 2 + op) << 15);
    gl2lds16(gbase + (long)(sr + c * 64) * ld + (ktb + scol),
             reg + c * 8192 + tid * 16);
  };

  // swizzled read cols: phys = (kh<<6 | (lane>>4)<<4) ^ ((lane&7)<<4)
  const int colx0 = ((lane >> 4) << 4) ^ ((lane & 7) << 4);
  const int colx1 = (64 | ((lane >> 4) << 4)) ^ ((lane & 7) << 4);
  const int rbA = (wm * 128 + (lane & 15)) * 128;
  const int rbB = (wn * 64 + (lane & 15)) * 128;

  f32x4 acc[8][4] = {};
  bf16x8 a0[4], a1[4], b0[4], b1[4];

  auto rdA = [&](bf16x8* dst, const char* reg, int g, int colx) {
#pragma unroll
    for (int m = 0; m < 4; ++m)
      dst[m] = *(const bf16x8*)(reg + rbA + g * (64 * 128) + m * (16 * 128) + colx);
  };
  auto rdB = [&](bf16x8* dst, const char* reg, int colx) {
#pragma unroll
    for (int n = 0; n < 4; ++n)
      dst[n] = *(const bf16x8*)(reg + rbB + n * (16 * 128) + colx);
  };
  auto mfma16 = [&](const bf16x8* af, const bf16x8* bf_, int g) {
    __builtin_amdgcn_s_setprio(1);
#pragma unroll
    for (int m = 0; m < 4; ++m)
#pragma unroll
      for (int n = 0; n < 4; ++n)
        acc[g * 4 + m][n] = __builtin_amdgcn_mfma_f32_16x16x32_bf16(
            af[m], bf_[n], acc[g * 4 + m][n], 0, 0, 0);
    __builtin_amdgcn_s_setprio(0);
    __builtin_amdgcn_sched_barrier(0);
  };

  // prologue: stage tile 0 into buf 0; issue phase-0 frag reads
#pragma unroll
  for (int c = 0; c < 4; ++c) stageChunk(0, 0, c, Ac, 0);
#pragma unroll
  for (int c = 0; c < 4; ++c) stageChunk(0, 1, c, Bc, 0);
  asm volatile("s_waitcnt vmcnt(0)" ::: "memory");
  __builtin_amdgcn_s_barrier();
  rdA(a0, smem, 0, colx0);
  rdB(b0, smem + (1 << 15), colx0);

  const int nt = K >> 6;
  for (int t = 0; t < nt; ++t) {
    const int b = t & 1;
    const bool pf = (t + 1 < nt);
    const int ktb = (t + 1) << 7;
    const char* regA0 = smem + ((b * 2 + 0) << 15);
    const char* regB0 = smem + ((b * 2 + 1) << 15);
    const char* regA1 = smem + (((b ^ 1) * 2 + 0) << 15);
    const char* regB1 = smem + (((b ^ 1) * 2 + 1) << 15);

    // phase 0: compute (g0,kh0) on a0,b0; stage A-chunks t+1; read a1<-A(g1,kh0)
    if (pf) {
#pragma unroll
      for (int c = 0; c < 4; ++c) stageChunk(b ^ 1, 0, c, Ac, ktb);
    }
    rdA(a1, regA0, 1, colx0);
    asm volatile("s_waitcnt lgkmcnt(4)" ::: "memory");
    __builtin_amdgcn_sched_barrier(0);
    mfma16(a0, b0, 0);
    __builtin_amdgcn_s_barrier();

    // phase 1: compute (g1,kh0) on a1,b0; stage B-chunks t+1; read a0<-A(g0,kh1), b1<-B(kh1)
    if (pf) {
#pragma unroll
      for (int c = 0; c < 4; ++c) stageChunk(b ^ 1, 1, c, Bc, ktb);
    }
    rdA(a0, regA0, 0, colx1);
    rdB(b1, regB0, colx1);
    asm volatile("s_waitcnt lgkmcnt(8)" ::: "memory");
    __builtin_amdgcn_sched_barrier(0);
    mfma16(a1, b0, 1);
    __builtin_amdgcn_s_barrier();

    // phase 2: compute (g0,kh1) on a0,b1; read a1<-A(g1,kh1)
    rdA(a1, regA0, 1, colx1);
    asm volatile("s_waitcnt lgkmcnt(4)" ::: "memory");
    __builtin_amdgcn_sched_barrier(0);
    mfma16(a0, b1, 0);   // M-half 0, kh=1 accumulates into acc[0..3]
    __builtin_amdgcn_s_barrier();

    // phase 3: compute (g1,kh1) on a1,b1; cross-tile reads from buf b^1
    if (pf) {
      asm volatile("s_waitcnt vmcnt(0)" ::: "memory");  // tile t+1 fully staged (issued ph0-1)
      __builtin_amdgcn_s_barrier();
      rdA(a0, regA1, 0, colx0);
      rdB(b0, regB1, colx0);
      asm volatile("s_waitcnt lgkmcnt(8)" ::: "memory");
    } else {
      asm volatile("s_waitcnt lgkmcnt(0)" ::: "memory");
    }
    __builtin_amdgcn_sched_barrier(0);
    mfma16(a1, b1, 1);   // M-half 1, kh=1 accumulates into acc[4..7]
    __builtin_amdgcn_s_barrier();
  }

  // epilogue: C/D layout col=lane&15, row=(lane>>4)*4+reg  [m89/m91 verified]
  const long row0 = (long)bm * 256 + wm * 128 + (lane >> 4) * 4;
  const int col0 = bn * 256 + wn * 64 + (lane & 15);
  if constexpr (FUSEQKV) {
    const int tensor = bn >> 2;  // gx==12: 0=Q,1=K,2=V
    unsigned short* dst = (unsigned short*)C + ((long)tensor << 24);  // 16M elems apart
    const int colb0 = col0 - (tensor << 10);
#pragma unroll
    for (int m = 0; m < 8; ++m) {
#pragma unroll
      for (int n = 0; n < 4; ++n) {
        if (tensor < 2) {
#pragma unroll
          for (int r = 0; r < 4; ++r)
            dst[(row0 + m * 16 + r) * 1024 + colb0 + n * 16] = f2bf(acc[m][n][r]);
        } else {
          long row = row0 + m * 16;
          long base = ((row >> 11) << 21) + ((long)(colb0 + n * 16) << 11) + (row & 2047);
          ushort4 st;
          st.x = f2bf(acc[m][n][0]); st.y = f2bf(acc[m][n][1]);
          st.z = f2bf(acc[m][n][2]); st.w = f2bf(acc[m][n][3]);
          *(ushort4*)(dst + base) = st;
        }
      }
    }
  } else {
#pragma unroll
    for (int m = 0; m < 8; ++m) {
#pragma unroll
      for (int n = 0; n < 4; ++n) {
#pragma unroll
        for (int r = 0; r < 4; ++r) {
          long row = row0 + m * 16 + r;
          int col = col0 + n * 16;
          float v = acc[m][n][r] * alpha;
          if constexpr (sizeof(OutT) == 2)
            C[row * (long)N + col] = (OutT)f2bf(v);
          else
            C[row * (long)N + col] = v;
        }
      }
    }
  }
}

// in-place row softmax on bf16 rows of length C (C == 2048, 256 thr * 8)
__global__ __launch_bounds__(256) void softmax_inplace(unsigned short* __restrict__ s, int C) {
  __shared__ float red[8];
  long row = blockIdx.x;
  unsigned short* p = s + row * (long)C;
  int tid = threadIdx.x, lane = tid & 63, w = tid >> 6;
  bf16x8 raw = *(const bf16x8*)(p + tid * 8);
  float v[8];
  float mx = -3.4e38f;
#pragma unroll
  for (int j = 0; j < 8; ++j) { v[j] = bf2f((unsigned short)raw[j]); mx = fmaxf(mx, v[j]); }
#pragma unroll
  for (int o = 32; o > 0; o >>= 1) mx = fmaxf(mx, __shfl_xor(mx, o));
  if (lane == 0) red[w] = mx;
  __syncthreads();
  mx = fmaxf(fmaxf(red[0], red[1]), fmaxf(red[2], red[3]));
  float sum = 0.f;
#pragma unroll
  for (int j = 0; j < 8; ++j) { v[j] = __expf(v[j] - mx); sum += v[j]; }
#pragma unroll
  for (int o = 32; o > 0; o >>= 1) sum += __shfl_xor(sum, o);
  if (lane == 0) red[4 + w] = sum;
  __syncthreads();
  float inv = 1.f / (red[4] + red[5] + red[6] + red[7]);
  bf16x8 o8;
#pragma unroll
  for (int j = 0; j < 8; ++j) o8[j] = (short)f2bf(v[j] * inv);
  *(bf16x8*)(p + tid * 8) = o8;
}

extern "C" void kernel_launch(void* const* d_in, const int* in_sizes, int n_in,
                              void* d_out, int out_size, void* d_ws, size_t ws_size,
                              hipStream_t stream) {
  (void)in_sizes; (void)n_in; (void)out_size; (void)ws_size;
  const float* x  = (const float*)d_in[0];
  const float* Wq = (const float*)d_in[1];
  const float* Wk = (const float*)d_in[2];
  const float* Wv = (const float*)d_in[3];
  const float* Wo = (const float*)d_in[4];
  const int B = 8, S = 2048, D = 1024;
  const long MB = 1 << 20;
  char* w = (char*)d_ws;
  unsigned short* Wqb = (unsigned short*)(w + 0 * MB);   // Wq,Wk,Wv contiguous (6MB)
  unsigned short* Wob = (unsigned short*)(w + 6 * MB);
  unsigned short* xb  = (unsigned short*)(w + 8 * MB);
  unsigned short* qb  = (unsigned short*)(w + 40 * MB);
  unsigned short* kb  = (unsigned short*)(w + 72 * MB);  // qb+16M elems
  unsigned short* vt  = (unsigned short*)(w + 104 * MB); // qb+32M elems (V^T [B][D][S])
  unsigned short* wb  = xb;  // x dead after projections
  unsigned short* attn = (unsigned short*)d_out;
  float* out = (float*)d_out;

  long nx = (long)B * S * D;
  long nw = (long)D * D;

  const int LDSB = 131072;
  hipFuncSetAttribute((const void*)gemm_bt8<unsigned short, true>,
                      hipFuncAttributeMaxDynamicSharedMemorySize, LDSB);
  hipFuncSetAttribute((const void*)gemm_bt8<unsigned short, false>,
                      hipFuncAttributeMaxDynamicSharedMemorySize, LDSB);
  hipFuncSetAttribute((const void*)gemm_bt8<float, false>,
                      hipFuncAttributeMaxDynamicSharedMemorySize, LDSB);

  cast_f32_bf16_k<<<(int)(nx / 2048), 256, 0, stream>>>(x, xb, nx);
  dim3 gW((int)(nw / 2048), 1, 4);
  cast4_f32_bf16_k<<<gW, 256, 0, stream>>>(Wq, Wk, Wv, Wo, Wqb, nw);

  // fused QKV projection: [16384,1024] @ [3072,1024]^T; per-bn routing Q/K/V^T
  dim3 gF(3072 / 256, (B * S) / 256, 1);
  gemm_bt8<unsigned short, true><<<gF, 512, LDSB, stream>>>(
      xb, Wqb, qb, B * S, 3072, D, 0, 0, 0, 1.f);

  // scores = (1/32) q @ k^T -> bf16 in d_out
  dim3 gS(S / 256, S / 256, B);
  gemm_bt8<unsigned short, false><<<gS, 512, LDSB, stream>>>(qb, kb, attn, S, S, D,
      (long)S * D, (long)S * D, (long)S * S, 0.03125f);

  softmax_inplace<<<B * S, 256, 0, stream>>>(attn, S);

  // weighted = attn @ v  (vt is [D][S]) : per batch M=2048, N=1024, K=2048
  dim3 gPV(D / 256, S / 256, B);
  gemm_bt8<unsigned short, false><<<gPV, 512, LDSB, stream>>>(attn, vt, wb, S, D, S,
      (long)S * S, (long)D * S, (long)S * D, 1.f);

  // out = weighted @ Wo^T (fp32): M=16384, N=1024, K=1024
  dim3 gP(D / 256, (B * S) / 256, 1);
  gemm_bt8<float, false><<<gP, 512, LDSB, stream>>>(wb, Wob, out, B * S, D, D, 0, 0, 0, 1.f);
}